// Round 1
// baseline (192.747 us; speedup 1.0000x reference)
//
#include <hip/hip_runtime.h>
#include <math.h>

#define C_IN 256
#define P_CH 64
#define H_IMG 128
#define W_IMG 128
#define HW (H_IMG*W_IMG)
#define N_IMG 4
#define K_PROTO 8
#define BN_EPS 1e-5f

typedef unsigned short u16;
typedef __attribute__((ext_vector_type(4))) short bf16x4;
typedef __attribute__((ext_vector_type(8))) short bf16x8;
typedef __attribute__((ext_vector_type(4))) float f32x4;

// workspace layout (float offsets)
#define OFF_H    0                       // 4*64*16384 bf16 = 2097152 floats
#define OFF_MD   2097152                 // 65536 floats
#define OFF_BMM  (2097152 + 65536)       // 4 img * 64 tiles * {min,max} = 512 floats

__device__ __forceinline__ float silu_f(float x) { return x / (1.f + __expf(-x)); }

__device__ __forceinline__ u16 f2bf(float f) {   // round-to-nearest-even
    union { float f; unsigned u; } v; v.f = f;
    unsigned r = v.u + 0x7fffu + ((v.u >> 16) & 1u);
    return (u16)(r >> 16);
}
__device__ __forceinline__ float bf2f(u16 s) {
    union { unsigned u; float f; } v; v.u = ((unsigned)s) << 16; return v.f;
}

// ---------------- A: 1x1 conv (256->64) + BN + SiLU via bf16 MFMA -------------
// Block = 1 row (128 px) x 64 out. 4 waves; wave w: pixels [w*32, w*32+32).
// K=256 in 8 chunks of 32, double-buffered LDS, x converted fp32->bf16 on stage.
// BN fold of W is done inline during the B-stage (prep kernel eliminated).
#define LDA 36    // bf16 per pixel row (18-bank stride: conflict-free frag reads)
#define LDB 264   // bf16 per n row (16B-aligned, 2-way only)
__global__ __launch_bounds__(256) void conv1x1_kernel(
    const float* __restrict__ x, const float* __restrict__ w1,
    const float* __restrict__ bn1, u16* __restrict__ h)
{
    __shared__ u16 As[2][128 * LDA];   // 18432 B
    __shared__ u16 Bs[64 * LDB];       // 33792 B
    __shared__ float bias_s[64];
    int bx = blockIdx.x;
    int img = bx >> 7, row = bx & 127;
    int tid = threadIdx.x;
    int wid = tid >> 6, lane = tid & 63;
    int mm = lane & 15, kb = lane >> 4;

    // stage B once: thread t -> n = t>>2, k-quarter (t&3)*64, BN-folded on the fly
    {
        int n = tid >> 2, k0 = (tid & 3) * 64;
        float sc = bn1[n] * rsqrtf(bn1[192 + n] + BN_EPS);
        if ((tid & 3) == 0) bias_s[n] = bn1[64 + n] - bn1[128 + n] * sc;
        const float* src = w1 + n * 256 + k0;
        u16* dst = Bs + n * LDB + k0;
#pragma unroll
        for (int i = 0; i < 64; i += 4) {
            float4 v = *(const float4*)(src + i);
            ushort4 o;
            o.x = f2bf(v.x * sc); o.y = f2bf(v.y * sc);
            o.z = f2bf(v.z * sc); o.w = f2bf(v.w * sc);
            *(ushort4*)(dst + i) = o;
        }
    }

    // A staging: cp = tid>>4 -> channels {2cp,2cp+1}; pg = tid&15 -> px pg+16i
    int cp = tid >> 4, pg = tid & 15;
    const float* xbase = x + (size_t)img * C_IN * HW + row * W_IMG;
    {
        const float* xc0 = xbase + (size_t)(2 * cp) * HW;
        const float* xc1 = xc0 + HW;
#pragma unroll
        for (int i = 0; i < 8; ++i) {
            int px = pg + 16 * i;
            ushort2 pk; pk.x = f2bf(xc0[px]); pk.y = f2bf(xc1[px]);
            *(ushort2*)(&As[0][px * LDA + 2 * cp]) = pk;
        }
    }
    __syncthreads();

    f32x4 acc[2][4];
#pragma unroll
    for (int mt = 0; mt < 2; ++mt)
#pragma unroll
        for (int nt = 0; nt < 4; ++nt) acc[mt][nt] = (f32x4){0.f, 0.f, 0.f, 0.f};

    for (int k = 0; k < 8; ++k) {
        float p0[8], p1[8];
        if (k < 7) {
            const float* xc0 = xbase + (size_t)((k + 1) * 32 + 2 * cp) * HW;
            const float* xc1 = xc0 + HW;
#pragma unroll
            for (int i = 0; i < 8; ++i) {
                int px = pg + 16 * i;
                p0[i] = xc0[px]; p1[i] = xc1[px];
            }
        }

        const u16* Ab = As[k & 1];
        bf16x8 afrag[2], bfrag[4];
#pragma unroll
        for (int mt = 0; mt < 2; ++mt) {
            const u16* ap = Ab + (wid * 32 + mt * 16 + mm) * LDA + kb * 8;
            bf16x4 lo = *(const bf16x4*)ap;
            bf16x4 hi = *(const bf16x4*)(ap + 4);
            afrag[mt] = __builtin_shufflevector(lo, hi, 0, 1, 2, 3, 4, 5, 6, 7);
        }
#pragma unroll
        for (int nt = 0; nt < 4; ++nt)
            bfrag[nt] = *(const bf16x8*)(Bs + (nt * 16 + mm) * LDB + k * 32 + kb * 8);
#pragma unroll
        for (int mt = 0; mt < 2; ++mt)
#pragma unroll
            for (int nt = 0; nt < 4; ++nt)
                acc[mt][nt] = __builtin_amdgcn_mfma_f32_16x16x32_bf16(
                    afrag[mt], bfrag[nt], acc[mt][nt], 0, 0, 0);

        if (k < 7) {
            u16* An = As[(k + 1) & 1];
#pragma unroll
            for (int i = 0; i < 8; ++i) {
                int px = pg + 16 * i;
                ushort2 pk; pk.x = f2bf(p0[i]); pk.y = f2bf(p1[i]);
                *(ushort2*)(&An[px * LDA + 2 * cp]) = pk;
            }
        }
        __syncthreads();
    }

    // epilogue: D row = pixel = (lane>>4)*4+reg, col = n = lane&15
#pragma unroll
    for (int mt = 0; mt < 2; ++mt) {
        int pxb = wid * 32 + mt * 16 + kb * 4;
#pragma unroll
        for (int nt = 0; nt < 4; ++nt) {
            int n = nt * 16 + mm;
            float bb = bias_s[n];
            ushort4 o;
            o.x = f2bf(silu_f(acc[mt][nt][0] + bb));
            o.y = f2bf(silu_f(acc[mt][nt][1] + bb));
            o.z = f2bf(silu_f(acc[mt][nt][2] + bb));
            o.w = f2bf(silu_f(acc[mt][nt][3] + bb));
            *(ushort4*)(h + ((size_t)img * P_CH + n) * HW + row * W_IMG + pxb) = o;
        }
    }
}

// ---------------- B: DW3x3 + BN + SiLU fused with proto-distance (bf16 in) ---
// proto norms computed in-block; per-block min/max written to ws (no atomics,
// no init kernel needed).
__global__ __launch_bounds__(1024) void dwconv_dev_kernel(
    const u16* __restrict__ h, const float* __restrict__ dw,
    const float* __restrict__ bn2, const float* __restrict__ protos,
    float* __restrict__ md, float* __restrict__ bmm)
{
    __shared__ float smem[4 * 8 * 324];
    __shared__ float pnorm_s[K_PROTO];
    int img = blockIdx.x >> 6;
    int t = blockIdx.x & 63;
    int y0 = (t >> 3) << 4, x0 = (t & 7) << 4;
    int tid = threadIdx.x;
    int q = tid >> 8;
    int qtid = tid & 255;
    int ty = qtid >> 4, tx = qtid & 15;

    if (tid < K_PROTO) {
        const float4* pr = (const float4*)(protos + tid * 64);
        float s = 0.f;
#pragma unroll
        for (int i = 0; i < 16; ++i) {
            float4 v = pr[i];
            s += v.x * v.x + v.y * v.y + v.z * v.z + v.w * v.w;
        }
        pnorm_s[tid] = s;
    }

    const u16* himg = h + (size_t)img * P_CH * HW;
    float* qt = smem + q * (8 * 324);

    int  pre_off[11];
    bool pre_ok[11];
    bool pre_v[11];
#pragma unroll
    for (int r = 0; r < 11; ++r) {
        int l = qtid + r * 256;
        bool valid = l < 2592;
        int cl = l / 324;
        int rr = l - cl * 324;
        int ly = rr / 18, lx = rr - ly * 18;
        int yy = y0 - 1 + ly, xx = x0 - 1 + lx;
        bool inb = (yy >= 0) & (yy < H_IMG) & (xx >= 0) & (xx < W_IMG);
        pre_v[r] = valid;
        pre_ok[r] = valid && inb;
        pre_off[r] = cl * HW + (inb ? (yy * W_IMG + xx) : 0);
    }

    float norm2 = 0.f;
    float dot[K_PROTO];
#pragma unroll
    for (int k = 0; k < K_PROTO; ++k) dot[k] = 0.f;

    {
        const u16* hs = himg + (size_t)(q * 16) * HW;
#pragma unroll
        for (int r = 0; r < 11; ++r) {
            float v = pre_ok[r] ? bf2f(hs[pre_off[r]]) : 0.f;
            if (pre_v[r]) qt[qtid + r * 256] = v;
        }
    }
    __syncthreads();

    for (int k = 0; k < 2; ++k) {
        float pf[11];
        if (k == 0) {
            const u16* hs = himg + (size_t)(q * 16 + 8) * HW;
#pragma unroll
            for (int r = 0; r < 11; ++r)
                pf[r] = pre_ok[r] ? bf2f(hs[pre_off[r]]) : 0.f;
        }

        int c0 = q * 16 + k * 8;
#pragma unroll
        for (int cl = 0; cl < 8; ++cl) {
            int ch = c0 + cl;
            const float* tc = qt + cl * 324;
            const float* wch = dw + ch * 9;
            float s = 0.f;
#pragma unroll
            for (int dy = 0; dy < 3; ++dy)
#pragma unroll
                for (int dx = 0; dx < 3; ++dx)
                    s = fmaf(tc[(ty + dy) * 18 + tx + dx], wch[dy * 3 + dx], s);
            float g = bn2[ch], bb = bn2[64 + ch], m = bn2[128 + ch], vv = bn2[192 + ch];
            float scale = g * rsqrtf(vv + BN_EPS);
            float val = silu_f(scale * s + (bb - m * scale));
            norm2 = fmaf(val, val, norm2);
#pragma unroll
            for (int kk = 0; kk < K_PROTO; ++kk)
                dot[kk] = fmaf(val, protos[kk * 64 + ch], dot[kk]);
        }

        if (k == 0) {
            __syncthreads();
#pragma unroll
            for (int r = 0; r < 11; ++r)
                if (pre_v[r]) qt[qtid + r * 256] = pf[r];
            __syncthreads();
        }
    }
    __syncthreads();

    float* P = smem;
    {
        float* dst = P + (q * 256 + qtid) * 9;
        dst[0] = norm2;
#pragma unroll
        for (int kk = 0; kk < K_PROTO; ++kk) dst[1 + kk] = dot[kk];
    }
    __syncthreads();

    float wmin = 1e30f, wmax = -1e30f, mdv = 0.f;
    if (q == 0) {
        float n2 = 0.f, dd[K_PROTO];
#pragma unroll
        for (int kk = 0; kk < K_PROTO; ++kk) dd[kk] = 0.f;
#pragma unroll
        for (int qq = 0; qq < 4; ++qq) {
            const float* src = P + (qq * 256 + qtid) * 9;
            n2 += src[0];
#pragma unroll
            for (int kk = 0; kk < K_PROTO; ++kk) dd[kk] += src[1 + kk];
        }
        float d2min = 1e30f;
#pragma unroll
        for (int kk = 0; kk < K_PROTO; ++kk)
            d2min = fminf(d2min, n2 + pnorm_s[kk] - 2.f * dd[kk]);
        mdv = sqrtf(fmaxf(d2min, 0.f)) * (1.f / 1.000001f);
        md[img * HW + (y0 + ty) * W_IMG + (x0 + tx)] = mdv;
        wmin = mdv; wmax = mdv;
#pragma unroll
        for (int d = 32; d > 0; d >>= 1) {
            wmin = fminf(wmin, __shfl_xor(wmin, d));
            wmax = fmaxf(wmax, __shfl_xor(wmax, d));
        }
    }
    __syncthreads();
    if (q == 0 && (qtid & 63) == 0) {
        int wid = qtid >> 6;
        smem[wid * 2]     = wmin;
        smem[wid * 2 + 1] = wmax;
    }
    __syncthreads();
    if (tid == 0) {
        float bmin = fminf(fminf(smem[0], smem[2]), fminf(smem[4], smem[6]));
        float bmax = fmaxf(fmaxf(smem[1], smem[3]), fmaxf(smem[5], smem[7]));
        bmm[(img * 64 + t) * 2]     = bmin;
        bmm[(img * 64 + t) * 2 + 1] = bmax;
    }
}

// ---------------- C: minmax-reduce + normalize + attention + apply -----------
// grid = img(4) x tile(64) x cg(4); block computes the 16x16 attn tile
// (redundant per cg, trivial) then streams 64 channels of x -> out with
// 16 float4 loads in flight per thread.
__global__ __launch_bounds__(256) void attn_final_kernel(
    const float* __restrict__ x, const float* __restrict__ md,
    const float* __restrict__ bmm,
    const float* __restrict__ bs_dw, const float* __restrict__ bs_bn1,
    const float* __restrict__ bs_pw, const float* __restrict__ bs_bn2,
    const float* __restrict__ bl_dw, const float* __restrict__ bl_bn1,
    const float* __restrict__ bl_pw, const float* __restrict__ bl_bn2,
    const float* __restrict__ fuse_w, const float* __restrict__ fuse_b,
    const float* __restrict__ gamma, float* __restrict__ out)
{
    __shared__ float tile[20 * 20];
    __shared__ __align__(16) float attn_s[256];
    __shared__ float mmred[2];
    int bx = blockIdx.x;
    int img = bx >> 8;
    int t = (bx >> 2) & 63;
    int cg = bx & 3;
    int y0 = (t >> 3) << 4, x0 = (t & 7) << 4;
    int tid = threadIdx.x;
    int ty = tid >> 4, tx = tid & 15;

    // per-image min/max from 64 per-block pairs (wave 0)
    if (tid < 64) {
        float mn = bmm[(img * 64 + tid) * 2];
        float mx = bmm[(img * 64 + tid) * 2 + 1];
#pragma unroll
        for (int d = 32; d > 0; d >>= 1) {
            mn = fminf(mn, __shfl_xor(mn, d));
            mx = fmaxf(mx, __shfl_xor(mx, d));
        }
        if (tid == 0) { mmred[0] = mn; mmred[1] = mx; }
    }
    __syncthreads();

    float fdmin = mmred[0];
    float fdmax = mmred[1];
    float inv = 1.f / (fdmax - fdmin + 1e-6f);

    const float* mdi = md + img * HW;
    for (int l = tid; l < 400; l += 256) {
        int ly = l / 20, lx = l - ly * 20;
        int yy = y0 - 2 + ly, xx = x0 - 2 + lx;
        float v = 0.f;
        if (yy >= 0 && yy < H_IMG && xx >= 0 && xx < W_IMG)
            v = (mdi[yy * W_IMG + xx] - fdmin) * inv;
        tile[l] = v;
    }
    __syncthreads();

    float c3 = 0.f;
#pragma unroll
    for (int dy = 0; dy < 3; ++dy)
#pragma unroll
        for (int dx = 0; dx < 3; ++dx)
            c3 = fmaf(tile[(ty + 1 + dy) * 20 + tx + 1 + dx], bs_dw[dy * 3 + dx], c3);
    float c5 = 0.f;
#pragma unroll
    for (int dy = 0; dy < 5; ++dy)
#pragma unroll
        for (int dx = 0; dx < 5; ++dx)
            c5 = fmaf(tile[(ty + dy) * 20 + tx + dx], bl_dw[dy * 5 + dx], c5);

    float s1 = bs_bn1[0] * rsqrtf(bs_bn1[3] + BN_EPS);
    float t1 = silu_f(s1 * c3 + (bs_bn1[1] - bs_bn1[2] * s1));
    float s2 = bl_bn1[0] * rsqrtf(bl_bn1[3] + BN_EPS);
    float t2 = silu_f(s2 * c5 + (bl_bn1[1] - bl_bn1[2] * s2));

    float acc = fuse_b[0];
#pragma unroll
    for (int c = 0; c < 8; ++c) {
        float scs = bs_bn2[c] * rsqrtf(bs_bn2[24 + c] + BN_EPS);
        float u1 = silu_f(scs * (bs_pw[c] * t1) + (bs_bn2[8 + c] - bs_bn2[16 + c] * scs));
        acc = fmaf(fuse_w[c], u1, acc);
        float scl = bl_bn2[c] * rsqrtf(bl_bn2[24 + c] + BN_EPS);
        float u2 = silu_f(scl * (bl_pw[c] * t2) + (bl_bn2[8 + c] - bl_bn2[16 + c] * scl));
        acc = fmaf(fuse_w[8 + c], u2, acc);
    }
    attn_s[tid] = 1.f / (1.f + __expf(-acc));
    __syncthreads();

    // apply: thread -> pixel-quad j (16 rows x 4 float4) and channel slice cs
    int j = tid & 63, cs = tid >> 6;
    int yy = y0 + (j >> 2), xq = x0 + (j & 3) * 4;
    float4 am = *(const float4*)&attn_s[(j >> 2) * 16 + (j & 3) * 4];
    float g = gamma[0];
    float m0 = 1.f + g * am.x, m1 = 1.f + g * am.y;
    float m2 = 1.f + g * am.z, m3 = 1.f + g * am.w;
    size_t base = ((size_t)(img * C_IN + cg * 64 + cs * 16)) * HW
                + (size_t)yy * W_IMG + xq;
#pragma unroll
    for (int c = 0; c < 16; ++c) {
        const float4 xv = *(const float4*)(x + base + (size_t)c * HW);
        float4 o;
        o.x = xv.x * m0; o.y = xv.y * m1; o.z = xv.z * m2; o.w = xv.w * m3;
        *(float4*)(out + base + (size_t)c * HW) = o;
    }
}

extern "C" void kernel_launch(void* const* d_in, const int* in_sizes, int n_in,
                              void* d_out, int out_size, void* d_ws, size_t ws_size,
                              hipStream_t stream) {
    const float* x      = (const float*)d_in[0];
    const float* fp_w1  = (const float*)d_in[1];
    const float* fp_bn1 = (const float*)d_in[2];
    const float* fp_dw  = (const float*)d_in[3];
    const float* fp_bn2 = (const float*)d_in[4];
    const float* protos = (const float*)d_in[5];
    const float* bs_dw  = (const float*)d_in[6];
    const float* bs_bn1 = (const float*)d_in[7];
    const float* bs_pw  = (const float*)d_in[8];
    const float* bs_bn2 = (const float*)d_in[9];
    const float* bl_dw  = (const float*)d_in[10];
    const float* bl_bn1 = (const float*)d_in[11];
    const float* bl_pw  = (const float*)d_in[12];
    const float* bl_bn2 = (const float*)d_in[13];
    const float* fuse_w = (const float*)d_in[14];
    const float* fuse_b = (const float*)d_in[15];
    const float* gamma  = (const float*)d_in[16];
    float* ws  = (float*)d_ws;
    float* out = (float*)d_out;

    conv1x1_kernel<<<512, 256, 0, stream>>>(x, fp_w1, fp_bn1, (u16*)(ws + OFF_H));
    dwconv_dev_kernel<<<256, 1024, 0, stream>>>((const u16*)(ws + OFF_H), fp_dw, fp_bn2,
                                                protos, ws + OFF_MD, ws + OFF_BMM);
    attn_final_kernel<<<1024, 256, 0, stream>>>(x, ws + OFF_MD, ws + OFF_BMM,
                                                bs_dw, bs_bn1, bs_pw, bs_bn2,
                                                bl_dw, bl_bn1, bl_pw, bl_bn2,
                                                fuse_w, fuse_b, gamma, out);
}

// Round 3
// 184.740 us; speedup vs baseline: 1.0433x; 1.0433x over previous
//
#include <hip/hip_runtime.h>
#include <math.h>

#define C_IN 256
#define P_CH 64
#define H_IMG 128
#define W_IMG 128
#define HW (H_IMG*W_IMG)
#define K_PROTO 8
#define BN_EPS 1e-5f

typedef unsigned short u16;
typedef __attribute__((ext_vector_type(4))) short bf16x4;
typedef __attribute__((ext_vector_type(8))) short bf16x8;
typedef __attribute__((ext_vector_type(4))) float f32x4;

// workspace layout (float offsets)
#define OFF_H    0                       // 4*64*16384 bf16 = 2097152 floats
#define OFF_MD   2097152                 // 65536 floats
#define OFF_BMM  (2097152 + 65536)       // 4*64*{min,max} = 512 floats
#define OFF_ATTN (OFF_BMM + 512)         // 65536 floats

__device__ __forceinline__ float silu_f(float x) { return x / (1.f + __expf(-x)); }

__device__ __forceinline__ u16 f2bf(float f) {   // round-to-nearest-even
    union { float f; unsigned u; } v; v.f = f;
    unsigned r = v.u + 0x7fffu + ((v.u >> 16) & 1u);
    return (u16)(r >> 16);
}
__device__ __forceinline__ float bf2f(u16 s) {
    union { unsigned u; float f; } v; v.u = ((unsigned)s) << 16; return v.f;
}

// ---------------- A: 1x1 conv (256->64) + BN + SiLU via bf16 MFMA -------------
// Block = 1 row (128 px) x 64 out. 4 waves; wave w: pixels [w*32, w*32+32).
// K=256 in 8 chunks of 32, double-buffered LDS.
// Staging: thread -> (ch = tid>>3, q = tid&7); float4 loads (16B/lane, lanes of
// one channel cover 128B contiguous), bf16 scatter into [px][k] LDS layout.
#define LDA 36    // bf16 per pixel row (conflict-free frag reads)
#define LDB 264   // bf16 per n row (16B-aligned, 2-way only)
__global__ __launch_bounds__(256) void conv1x1_kernel(
    const float* __restrict__ x, const float* __restrict__ w1,
    const float* __restrict__ bn1, u16* __restrict__ h)
{
    __shared__ u16 As[2][128 * LDA];   // 18432 B
    __shared__ u16 Bs[64 * LDB];       // 33792 B
    __shared__ float bias_s[64];
    int bx = blockIdx.x;
    int img = bx >> 7, row = bx & 127;
    int tid = threadIdx.x;
    int wid = tid >> 6, lane = tid & 63;
    int mm = lane & 15, kb = lane >> 4;

    // stage B once: thread t -> n = t>>2, k-quarter (t&3)*64, BN-folded on the fly
    {
        int n = tid >> 2, k0 = (tid & 3) * 64;
        float sc = bn1[n] * rsqrtf(bn1[192 + n] + BN_EPS);
        if ((tid & 3) == 0) bias_s[n] = bn1[64 + n] - bn1[128 + n] * sc;
        const float* src = w1 + n * 256 + k0;
        u16* dst = Bs + n * LDB + k0;
#pragma unroll
        for (int i = 0; i < 64; i += 4) {
            float4 v = *(const float4*)(src + i);
            ushort4 o;
            o.x = f2bf(v.x * sc); o.y = f2bf(v.y * sc);
            o.z = f2bf(v.z * sc); o.w = f2bf(v.w * sc);
            *(ushort4*)(dst + i) = o;
        }
    }

    // A staging mapping: ch = tid>>3 (0..31 within k-chunk), q = tid&7
    int sch = tid >> 3, sq = tid & 7;
    const float* xbase = x + (size_t)img * C_IN * HW + row * W_IMG;
    {
        const float* xc = xbase + (size_t)sch * HW;
#pragma unroll
        for (int i = 0; i < 4; ++i) {
            int px0 = sq * 4 + i * 32;
            float4 v = *(const float4*)(xc + px0);
            u16* d = &As[0][px0 * LDA + sch];
            d[0]       = f2bf(v.x);
            d[LDA]     = f2bf(v.y);
            d[2 * LDA] = f2bf(v.z);
            d[3 * LDA] = f2bf(v.w);
        }
    }
    __syncthreads();

    f32x4 acc[2][4];
#pragma unroll
    for (int mt = 0; mt < 2; ++mt)
#pragma unroll
        for (int nt = 0; nt < 4; ++nt) acc[mt][nt] = (f32x4){0.f, 0.f, 0.f, 0.f};

    for (int k = 0; k < 8; ++k) {
        float4 pf[4];
        if (k < 7) {
            const float* xc = xbase + (size_t)((k + 1) * 32 + sch) * HW;
#pragma unroll
            for (int i = 0; i < 4; ++i)
                pf[i] = *(const float4*)(xc + sq * 4 + i * 32);
        }

        const u16* Ab = As[k & 1];
        bf16x8 afrag[2], bfrag[4];
#pragma unroll
        for (int mt = 0; mt < 2; ++mt) {
            const u16* ap = Ab + (wid * 32 + mt * 16 + mm) * LDA + kb * 8;
            bf16x4 lo = *(const bf16x4*)ap;
            bf16x4 hi = *(const bf16x4*)(ap + 4);
            afrag[mt] = __builtin_shufflevector(lo, hi, 0, 1, 2, 3, 4, 5, 6, 7);
        }
#pragma unroll
        for (int nt = 0; nt < 4; ++nt)
            bfrag[nt] = *(const bf16x8*)(Bs + (nt * 16 + mm) * LDB + k * 32 + kb * 8);
#pragma unroll
        for (int mt = 0; mt < 2; ++mt)
#pragma unroll
            for (int nt = 0; nt < 4; ++nt)
                acc[mt][nt] = __builtin_amdgcn_mfma_f32_16x16x32_bf16(
                    afrag[mt], bfrag[nt], acc[mt][nt], 0, 0, 0);

        if (k < 7) {
            u16* An = As[(k + 1) & 1];
#pragma unroll
            for (int i = 0; i < 4; ++i) {
                int px0 = sq * 4 + i * 32;
                u16* d = &An[px0 * LDA + sch];
                d[0]       = f2bf(pf[i].x);
                d[LDA]     = f2bf(pf[i].y);
                d[2 * LDA] = f2bf(pf[i].z);
                d[3 * LDA] = f2bf(pf[i].w);
            }
        }
        __syncthreads();
    }

    // epilogue: D row = pixel = (lane>>4)*4+reg, col = n = lane&15
#pragma unroll
    for (int mt = 0; mt < 2; ++mt) {
        int pxb = wid * 32 + mt * 16 + kb * 4;
#pragma unroll
        for (int nt = 0; nt < 4; ++nt) {
            int n = nt * 16 + mm;
            float bb = bias_s[n];
            ushort4 o;
            o.x = f2bf(silu_f(acc[mt][nt][0] + bb));
            o.y = f2bf(silu_f(acc[mt][nt][1] + bb));
            o.z = f2bf(silu_f(acc[mt][nt][2] + bb));
            o.w = f2bf(silu_f(acc[mt][nt][3] + bb));
            *(ushort4*)(h + ((size_t)img * P_CH + n) * HW + row * W_IMG + pxb) = o;
        }
    }
}

// ---------------- B: DW3x3 + BN + SiLU fused with proto-distance (bf16 in) ---
__global__ __launch_bounds__(1024) void dwconv_dev_kernel(
    const u16* __restrict__ h, const float* __restrict__ dw,
    const float* __restrict__ bn2, const float* __restrict__ protos,
    float* __restrict__ md, float* __restrict__ bmm)
{
    __shared__ float smem[4 * 8 * 324];
    __shared__ float pnorm_s[K_PROTO];
    int img = blockIdx.x >> 6;
    int t = blockIdx.x & 63;
    int y0 = (t >> 3) << 4, x0 = (t & 7) << 4;
    int tid = threadIdx.x;
    int q = tid >> 8;
    int qtid = tid & 255;
    int ty = qtid >> 4, tx = qtid & 15;

    if (tid < K_PROTO) {
        const float4* pr = (const float4*)(protos + tid * 64);
        float s = 0.f;
#pragma unroll
        for (int i = 0; i < 16; ++i) {
            float4 v = pr[i];
            s += v.x * v.x + v.y * v.y + v.z * v.z + v.w * v.w;
        }
        pnorm_s[tid] = s;
    }

    const u16* himg = h + (size_t)img * P_CH * HW;
    float* qt = smem + q * (8 * 324);

    int  pre_off[11];
    bool pre_ok[11];
    bool pre_v[11];
#pragma unroll
    for (int r = 0; r < 11; ++r) {
        int l = qtid + r * 256;
        bool valid = l < 2592;
        int cl = l / 324;
        int rr = l - cl * 324;
        int ly = rr / 18, lx = rr - ly * 18;
        int yy = y0 - 1 + ly, xx = x0 - 1 + lx;
        bool inb = (yy >= 0) & (yy < H_IMG) & (xx >= 0) & (xx < W_IMG);
        pre_v[r] = valid;
        pre_ok[r] = valid && inb;
        pre_off[r] = cl * HW + (inb ? (yy * W_IMG + xx) : 0);
    }

    float norm2 = 0.f;
    float dot[K_PROTO];
#pragma unroll
    for (int k = 0; k < K_PROTO; ++k) dot[k] = 0.f;

    {
        const u16* hs = himg + (size_t)(q * 16) * HW;
#pragma unroll
        for (int r = 0; r < 11; ++r) {
            float v = pre_ok[r] ? bf2f(hs[pre_off[r]]) : 0.f;
            if (pre_v[r]) qt[qtid + r * 256] = v;
        }
    }
    __syncthreads();

    for (int k = 0; k < 2; ++k) {
        float pf[11];
        if (k == 0) {
            const u16* hs = himg + (size_t)(q * 16 + 8) * HW;
#pragma unroll
            for (int r = 0; r < 11; ++r)
                pf[r] = pre_ok[r] ? bf2f(hs[pre_off[r]]) : 0.f;
        }

        int c0 = q * 16 + k * 8;
#pragma unroll
        for (int cl = 0; cl < 8; ++cl) {
            int ch = c0 + cl;
            const float* tc = qt + cl * 324;
            const float* wch = dw + ch * 9;
            float s = 0.f;
#pragma unroll
            for (int dy = 0; dy < 3; ++dy)
#pragma unroll
                for (int dx = 0; dx < 3; ++dx)
                    s = fmaf(tc[(ty + dy) * 18 + tx + dx], wch[dy * 3 + dx], s);
            float g = bn2[ch], bb = bn2[64 + ch], m = bn2[128 + ch], vv = bn2[192 + ch];
            float scale = g * rsqrtf(vv + BN_EPS);
            float val = silu_f(scale * s + (bb - m * scale));
            norm2 = fmaf(val, val, norm2);
#pragma unroll
            for (int kk = 0; kk < K_PROTO; ++kk)
                dot[kk] = fmaf(val, protos[kk * 64 + ch], dot[kk]);
        }

        if (k == 0) {
            __syncthreads();
#pragma unroll
            for (int r = 0; r < 11; ++r)
                if (pre_v[r]) qt[qtid + r * 256] = pf[r];
            __syncthreads();
        }
    }
    __syncthreads();

    float* P = smem;
    {
        float* dst = P + (q * 256 + qtid) * 9;
        dst[0] = norm2;
#pragma unroll
        for (int kk = 0; kk < K_PROTO; ++kk) dst[1 + kk] = dot[kk];
    }
    __syncthreads();

    float wmin = 1e30f, wmax = -1e30f;
    if (q == 0) {
        float n2 = 0.f, dd[K_PROTO];
#pragma unroll
        for (int kk = 0; kk < K_PROTO; ++kk) dd[kk] = 0.f;
#pragma unroll
        for (int qq = 0; qq < 4; ++qq) {
            const float* src = P + (qq * 256 + qtid) * 9;
            n2 += src[0];
#pragma unroll
            for (int kk = 0; kk < K_PROTO; ++kk) dd[kk] += src[1 + kk];
        }
        float d2min = 1e30f;
#pragma unroll
        for (int kk = 0; kk < K_PROTO; ++kk)
            d2min = fminf(d2min, n2 + pnorm_s[kk] - 2.f * dd[kk]);
        float mdv = sqrtf(fmaxf(d2min, 0.f)) * (1.f / 1.000001f);
        md[img * HW + (y0 + ty) * W_IMG + (x0 + tx)] = mdv;
        wmin = mdv; wmax = mdv;
#pragma unroll
        for (int d = 32; d > 0; d >>= 1) {
            wmin = fminf(wmin, __shfl_xor(wmin, d));
            wmax = fmaxf(wmax, __shfl_xor(wmax, d));
        }
    }
    __syncthreads();
    if (q == 0 && (qtid & 63) == 0) {
        int wd = qtid >> 6;
        smem[wd * 2]     = wmin;
        smem[wd * 2 + 1] = wmax;
    }
    __syncthreads();
    if (tid == 0) {
        float bmin = fminf(fminf(smem[0], smem[2]), fminf(smem[4], smem[6]));
        float bmax = fmaxf(fmaxf(smem[1], smem[3]), fmaxf(smem[5], smem[7]));
        bmm[(img * 64 + t) * 2]     = bmin;
        bmm[(img * 64 + t) * 2 + 1] = bmax;
    }
}

// ---------------- C: minmax-reduce + normalize + attention head --------------
__global__ __launch_bounds__(256) void attn_kernel(
    const float* __restrict__ md, const float* __restrict__ bmm,
    const float* __restrict__ bs_dw, const float* __restrict__ bs_bn1,
    const float* __restrict__ bs_pw, const float* __restrict__ bs_bn2,
    const float* __restrict__ bl_dw, const float* __restrict__ bl_bn1,
    const float* __restrict__ bl_pw, const float* __restrict__ bl_bn2,
    const float* __restrict__ fuse_w, const float* __restrict__ fuse_b,
    float* __restrict__ attn)
{
    __shared__ float tile[20 * 20];
    __shared__ float mmred[2];
    int img = blockIdx.x >> 6;
    int t = blockIdx.x & 63;
    int y0 = (t >> 3) << 4, x0 = (t & 7) << 4;
    int tid = threadIdx.x;
    int ty = tid >> 4, tx = tid & 15;

    if (tid < 64) {
        float mn = bmm[(img * 64 + tid) * 2];
        float mx = bmm[(img * 64 + tid) * 2 + 1];
#pragma unroll
        for (int d = 32; d > 0; d >>= 1) {
            mn = fminf(mn, __shfl_xor(mn, d));
            mx = fmaxf(mx, __shfl_xor(mx, d));
        }
        if (tid == 0) { mmred[0] = mn; mmred[1] = mx; }
    }
    __syncthreads();

    float fdmin = mmred[0];
    float inv = 1.f / (mmred[1] - fdmin + 1e-6f);

    const float* mdi = md + img * HW;
    for (int l = tid; l < 400; l += 256) {
        int ly = l / 20, lx = l - ly * 20;
        int yy = y0 - 2 + ly, xx = x0 - 2 + lx;
        float v = 0.f;
        if (yy >= 0 && yy < H_IMG && xx >= 0 && xx < W_IMG)
            v = (mdi[yy * W_IMG + xx] - fdmin) * inv;
        tile[l] = v;
    }
    __syncthreads();

    float c3 = 0.f;
#pragma unroll
    for (int dy = 0; dy < 3; ++dy)
#pragma unroll
        for (int dx = 0; dx < 3; ++dx)
            c3 = fmaf(tile[(ty + 1 + dy) * 20 + tx + 1 + dx], bs_dw[dy * 3 + dx], c3);
    float c5 = 0.f;
#pragma unroll
    for (int dy = 0; dy < 5; ++dy)
#pragma unroll
        for (int dx = 0; dx < 5; ++dx)
            c5 = fmaf(tile[(ty + dy) * 20 + tx + dx], bl_dw[dy * 5 + dx], c5);

    float s1 = bs_bn1[0] * rsqrtf(bs_bn1[3] + BN_EPS);
    float t1 = silu_f(s1 * c3 + (bs_bn1[1] - bs_bn1[2] * s1));
    float s2 = bl_bn1[0] * rsqrtf(bl_bn1[3] + BN_EPS);
    float t2 = silu_f(s2 * c5 + (bl_bn1[1] - bl_bn1[2] * s2));

    float acc = fuse_b[0];
#pragma unroll
    for (int c = 0; c < 8; ++c) {
        float scs = bs_bn2[c] * rsqrtf(bs_bn2[24 + c] + BN_EPS);
        float u1 = silu_f(scs * (bs_pw[c] * t1) + (bs_bn2[8 + c] - bs_bn2[16 + c] * scs));
        acc = fmaf(fuse_w[c], u1, acc);
        float scl = bl_bn2[c] * rsqrtf(bl_bn2[24 + c] + BN_EPS);
        float u2 = silu_f(scl * (bl_pw[c] * t2) + (bl_bn2[8 + c] - bl_bn2[16 + c] * scl));
        acc = fmaf(fuse_w[8 + c], u2, acc);
    }
    attn[img * HW + (y0 + ty) * W_IMG + (x0 + tx)] = 1.f / (1.f + __expf(-acc));
}

// ---------------- D: out = x * (1 + gamma * attn), linear coalesced ----------
__global__ __launch_bounds__(256) void final_kernel(
    const float* __restrict__ x, const float* __restrict__ attn,
    const float* __restrict__ gamma, float* __restrict__ out)
{
    float g = gamma[0];
    size_t f4 = (size_t)blockIdx.x * 256 + threadIdx.x;
#pragma unroll
    for (int c = 0; c < 4; ++c) {
        size_t i = (f4 + (size_t)c * 1048576) * 4;   // float index
        int img_i = (int)(i >> 22);                  // / (256*16384)
        int hw    = (int)(i & (size_t)(HW - 1));
        float4 av = *(const float4*)(attn + ((size_t)img_i << 14) + hw);
        float4 xv = *(const float4*)(x + i);
        float4 o;
        o.x = xv.x * (1.f + g * av.x);
        o.y = xv.y * (1.f + g * av.y);
        o.z = xv.z * (1.f + g * av.z);
        o.w = xv.w * (1.f + g * av.w);
        *(float4*)(out + i) = o;
    }
}

extern "C" void kernel_launch(void* const* d_in, const int* in_sizes, int n_in,
                              void* d_out, int out_size, void* d_ws, size_t ws_size,
                              hipStream_t stream) {
    const float* x      = (const float*)d_in[0];
    const float* fp_w1  = (const float*)d_in[1];
    const float* fp_bn1 = (const float*)d_in[2];
    const float* fp_dw  = (const float*)d_in[3];
    const float* fp_bn2 = (const float*)d_in[4];
    const float* protos = (const float*)d_in[5];
    const float* bs_dw  = (const float*)d_in[6];
    const float* bs_bn1 = (const float*)d_in[7];
    const float* bs_pw  = (const float*)d_in[8];
    const float* bs_bn2 = (const float*)d_in[9];
    const float* bl_dw  = (const float*)d_in[10];
    const float* bl_bn1 = (const float*)d_in[11];
    const float* bl_pw  = (const float*)d_in[12];
    const float* bl_bn2 = (const float*)d_in[13];
    const float* fuse_w = (const float*)d_in[14];
    const float* fuse_b = (const float*)d_in[15];
    const float* gamma  = (const float*)d_in[16];
    float* ws  = (float*)d_ws;
    float* out = (float*)d_out;

    conv1x1_kernel<<<512, 256, 0, stream>>>(x, fp_w1, fp_bn1, (u16*)(ws + OFF_H));
    dwconv_dev_kernel<<<256, 1024, 0, stream>>>((const u16*)(ws + OFF_H), fp_dw, fp_bn2,
                                                protos, ws + OFF_MD, ws + OFF_BMM);
    attn_kernel<<<256, 256, 0, stream>>>(ws + OFF_MD, ws + OFF_BMM,
                                         bs_dw, bs_bn1, bs_pw, bs_bn2,
                                         bl_dw, bl_bn1, bl_pw, bl_bn2,
                                         fuse_w, fuse_b, ws + OFF_ATTN);
    final_kernel<<<4096, 256, 0, stream>>>(x, ws + OFF_ATTN, gamma, out);
}

// Round 4
// 183.982 us; speedup vs baseline: 1.0476x; 1.0041x over previous
//
#include <hip/hip_runtime.h>
#include <math.h>

#define C_IN 256
#define P_CH 64
#define H_IMG 128
#define W_IMG 128
#define HW (H_IMG*W_IMG)
#define K_PROTO 8
#define BN_EPS 1e-5f

typedef unsigned short u16;
typedef __attribute__((ext_vector_type(4))) short bf16x4;
typedef __attribute__((ext_vector_type(8))) short bf16x8;
typedef __attribute__((ext_vector_type(4))) float f32x4;

// workspace layout (float offsets)
#define OFF_H    0                       // 4*64*16384 bf16 = 2097152 floats
#define OFF_MD   2097152                 // 65536 floats
#define OFF_BMM  (2097152 + 65536)       // 4*64*{min,max} = 512 floats
#define OFF_ATTN (OFF_BMM + 512)         // 65536 floats

__device__ __forceinline__ float silu_f(float x) { return x / (1.f + __expf(-x)); }

__device__ __forceinline__ u16 f2bf(float f) {   // round-to-nearest-even
    union { float f; unsigned u; } v; v.f = f;
    unsigned r = v.u + 0x7fffu + ((v.u >> 16) & 1u);
    return (u16)(r >> 16);
}
__device__ __forceinline__ float bf2f(u16 s) {
    union { unsigned u; float f; } v; v.u = ((unsigned)s) << 16; return v.f;
}

// ---------------- A: 1x1 conv (256->64) + BN + SiLU via bf16 MFMA -------------
// Block = 1 row (128 px) x 64 out. 8 waves (512 thr): wave w owns px-tile
// [w*16, w*16+16) x 4 n-tiles -> 16 waves/CU at 512 blocks (was 8 with 256 thr).
// K=256 in 8 chunks of 32, double-buffered LDS, register prefetch.
#define LDA 36    // bf16 per pixel row (18-bank stride: conflict-free frag reads)
#define LDB 264   // bf16 per n row (16B-aligned, 2-way only)
__global__ __launch_bounds__(512) void conv1x1_kernel(
    const float* __restrict__ x, const float* __restrict__ w1,
    const float* __restrict__ bn1, u16* __restrict__ h)
{
    __shared__ u16 As[2][128 * LDA];   // 18432 B
    __shared__ u16 Bs[64 * LDB];       // 33792 B
    __shared__ float bias_s[64];
    int bx = blockIdx.x;
    int img = bx >> 7, row = bx & 127;
    int tid = threadIdx.x;
    int wid = tid >> 6, lane = tid & 63;
    int mm = lane & 15, kb = lane >> 4;

    // stage B once: thread t -> n = t>>3, k-eighth (t&7)*32, BN-folded on the fly
    {
        int n = tid >> 3, k0 = (tid & 7) * 32;
        float sc = bn1[n] * rsqrtf(bn1[192 + n] + BN_EPS);
        if ((tid & 7) == 0) bias_s[n] = bn1[64 + n] - bn1[128 + n] * sc;
        const float* src = w1 + n * 256 + k0;
        u16* dst = Bs + n * LDB + k0;
#pragma unroll
        for (int i = 0; i < 32; i += 4) {
            float4 v = *(const float4*)(src + i);
            ushort4 o;
            o.x = f2bf(v.x * sc); o.y = f2bf(v.y * sc);
            o.z = f2bf(v.z * sc); o.w = f2bf(v.w * sc);
            *(ushort4*)(dst + i) = o;
        }
    }

    // A staging mapping: ch = tid>>4 (0..31 in k-chunk), sq = tid&15;
    // px0 = sq*4 + i*64 -> 16 lanes cover 256B contiguous per channel.
    int sch = tid >> 4, sq = tid & 15;
    const float* xbase = x + (size_t)img * C_IN * HW + row * W_IMG;
    {
        const float* xc = xbase + (size_t)sch * HW;
#pragma unroll
        for (int i = 0; i < 2; ++i) {
            int px0 = sq * 4 + i * 64;
            float4 v = *(const float4*)(xc + px0);
            u16* d = &As[0][px0 * LDA + sch];
            d[0]       = f2bf(v.x);
            d[LDA]     = f2bf(v.y);
            d[2 * LDA] = f2bf(v.z);
            d[3 * LDA] = f2bf(v.w);
        }
    }
    __syncthreads();

    f32x4 acc[4];
#pragma unroll
    for (int nt = 0; nt < 4; ++nt) acc[nt] = (f32x4){0.f, 0.f, 0.f, 0.f};

    for (int k = 0; k < 8; ++k) {
        float4 pf[2];
        if (k < 7) {
            const float* xc = xbase + (size_t)((k + 1) * 32 + sch) * HW;
            pf[0] = *(const float4*)(xc + sq * 4);
            pf[1] = *(const float4*)(xc + sq * 4 + 64);
        }

        const u16* Ab = As[k & 1];
        bf16x8 afrag, bfrag[4];
        {
            const u16* ap = Ab + (wid * 16 + mm) * LDA + kb * 8;
            bf16x4 lo = *(const bf16x4*)ap;
            bf16x4 hi = *(const bf16x4*)(ap + 4);
            afrag = __builtin_shufflevector(lo, hi, 0, 1, 2, 3, 4, 5, 6, 7);
        }
#pragma unroll
        for (int nt = 0; nt < 4; ++nt)
            bfrag[nt] = *(const bf16x8*)(Bs + (nt * 16 + mm) * LDB + k * 32 + kb * 8);
#pragma unroll
        for (int nt = 0; nt < 4; ++nt)
            acc[nt] = __builtin_amdgcn_mfma_f32_16x16x32_bf16(
                afrag, bfrag[nt], acc[nt], 0, 0, 0);

        if (k < 7) {
            u16* An = As[(k + 1) & 1];
#pragma unroll
            for (int i = 0; i < 2; ++i) {
                int px0 = sq * 4 + i * 64;
                u16* d = &An[px0 * LDA + sch];
                d[0]       = f2bf(pf[i].x);
                d[LDA]     = f2bf(pf[i].y);
                d[2 * LDA] = f2bf(pf[i].z);
                d[3 * LDA] = f2bf(pf[i].w);
            }
        }
        __syncthreads();
    }

    // epilogue: D row = pixel = (lane>>4)*4+reg, col = n = lane&15
    int pxb = wid * 16 + kb * 4;
#pragma unroll
    for (int nt = 0; nt < 4; ++nt) {
        int n = nt * 16 + mm;
        float bb = bias_s[n];
        ushort4 o;
        o.x = f2bf(silu_f(acc[nt][0] + bb));
        o.y = f2bf(silu_f(acc[nt][1] + bb));
        o.z = f2bf(silu_f(acc[nt][2] + bb));
        o.w = f2bf(silu_f(acc[nt][3] + bb));
        *(ushort4*)(h + ((size_t)img * P_CH + n) * HW + row * W_IMG + pxb) = o;
    }
}

// ---------------- B: DW3x3 + BN + SiLU fused with proto-distance (bf16 in) ---
__global__ __launch_bounds__(1024) void dwconv_dev_kernel(
    const u16* __restrict__ h, const float* __restrict__ dw,
    const float* __restrict__ bn2, const float* __restrict__ protos,
    float* __restrict__ md, float* __restrict__ bmm)
{
    __shared__ float smem[4 * 8 * 324];
    __shared__ float pnorm_s[K_PROTO];
    int img = blockIdx.x >> 6;
    int t = blockIdx.x & 63;
    int y0 = (t >> 3) << 4, x0 = (t & 7) << 4;
    int tid = threadIdx.x;
    int q = tid >> 8;
    int qtid = tid & 255;
    int ty = qtid >> 4, tx = qtid & 15;

    if (tid < K_PROTO) {
        const float4* pr = (const float4*)(protos + tid * 64);
        float s = 0.f;
#pragma unroll
        for (int i = 0; i < 16; ++i) {
            float4 v = pr[i];
            s += v.x * v.x + v.y * v.y + v.z * v.z + v.w * v.w;
        }
        pnorm_s[tid] = s;
    }

    const u16* himg = h + (size_t)img * P_CH * HW;
    float* qt = smem + q * (8 * 324);

    int  pre_off[11];
    bool pre_ok[11];
    bool pre_v[11];
#pragma unroll
    for (int r = 0; r < 11; ++r) {
        int l = qtid + r * 256;
        bool valid = l < 2592;
        int cl = l / 324;
        int rr = l - cl * 324;
        int ly = rr / 18, lx = rr - ly * 18;
        int yy = y0 - 1 + ly, xx = x0 - 1 + lx;
        bool inb = (yy >= 0) & (yy < H_IMG) & (xx >= 0) & (xx < W_IMG);
        pre_v[r] = valid;
        pre_ok[r] = valid && inb;
        pre_off[r] = cl * HW + (inb ? (yy * W_IMG + xx) : 0);
    }

    float norm2 = 0.f;
    float dot[K_PROTO];
#pragma unroll
    for (int k = 0; k < K_PROTO; ++k) dot[k] = 0.f;

    {
        const u16* hs = himg + (size_t)(q * 16) * HW;
#pragma unroll
        for (int r = 0; r < 11; ++r) {
            float v = pre_ok[r] ? bf2f(hs[pre_off[r]]) : 0.f;
            if (pre_v[r]) qt[qtid + r * 256] = v;
        }
    }
    __syncthreads();

    for (int k = 0; k < 2; ++k) {
        float pf[11];
        if (k == 0) {
            const u16* hs = himg + (size_t)(q * 16 + 8) * HW;
#pragma unroll
            for (int r = 0; r < 11; ++r)
                pf[r] = pre_ok[r] ? bf2f(hs[pre_off[r]]) : 0.f;
        }

        int c0 = q * 16 + k * 8;
#pragma unroll
        for (int cl = 0; cl < 8; ++cl) {
            int ch = c0 + cl;
            const float* tc = qt + cl * 324;
            const float* wch = dw + ch * 9;
            float s = 0.f;
#pragma unroll
            for (int dy = 0; dy < 3; ++dy)
#pragma unroll
                for (int dx = 0; dx < 3; ++dx)
                    s = fmaf(tc[(ty + dy) * 18 + tx + dx], wch[dy * 3 + dx], s);
            float g = bn2[ch], bb = bn2[64 + ch], m = bn2[128 + ch], vv = bn2[192 + ch];
            float scale = g * rsqrtf(vv + BN_EPS);
            float val = silu_f(scale * s + (bb - m * scale));
            norm2 = fmaf(val, val, norm2);
#pragma unroll
            for (int kk = 0; kk < K_PROTO; ++kk)
                dot[kk] = fmaf(val, protos[kk * 64 + ch], dot[kk]);
        }

        if (k == 0) {
            __syncthreads();
#pragma unroll
            for (int r = 0; r < 11; ++r)
                if (pre_v[r]) qt[qtid + r * 256] = pf[r];
            __syncthreads();
        }
    }
    __syncthreads();

    float* P = smem;
    {
        float* dst = P + (q * 256 + qtid) * 9;
        dst[0] = norm2;
#pragma unroll
        for (int kk = 0; kk < K_PROTO; ++kk) dst[1 + kk] = dot[kk];
    }
    __syncthreads();

    float wmin = 1e30f, wmax = -1e30f;
    if (q == 0) {
        float n2 = 0.f, dd[K_PROTO];
#pragma unroll
        for (int kk = 0; kk < K_PROTO; ++kk) dd[kk] = 0.f;
#pragma unroll
        for (int qq = 0; qq < 4; ++qq) {
            const float* src = P + (qq * 256 + qtid) * 9;
            n2 += src[0];
#pragma unroll
            for (int kk = 0; kk < K_PROTO; ++kk) dd[kk] += src[1 + kk];
        }
        float d2min = 1e30f;
#pragma unroll
        for (int kk = 0; kk < K_PROTO; ++kk)
            d2min = fminf(d2min, n2 + pnorm_s[kk] - 2.f * dd[kk]);
        float mdv = sqrtf(fmaxf(d2min, 0.f)) * (1.f / 1.000001f);
        md[img * HW + (y0 + ty) * W_IMG + (x0 + tx)] = mdv;
        wmin = mdv; wmax = mdv;
#pragma unroll
        for (int d = 32; d > 0; d >>= 1) {
            wmin = fminf(wmin, __shfl_xor(wmin, d));
            wmax = fmaxf(wmax, __shfl_xor(wmax, d));
        }
    }
    __syncthreads();
    if (q == 0 && (qtid & 63) == 0) {
        int wd = qtid >> 6;
        smem[wd * 2]     = wmin;
        smem[wd * 2 + 1] = wmax;
    }
    __syncthreads();
    if (tid == 0) {
        float bmin = fminf(fminf(smem[0], smem[2]), fminf(smem[4], smem[6]));
        float bmax = fmaxf(fmaxf(smem[1], smem[3]), fmaxf(smem[5], smem[7]));
        bmm[(img * 64 + t) * 2]     = bmin;
        bmm[(img * 64 + t) * 2 + 1] = bmax;
    }
}

// ---------------- C: minmax-reduce + normalize + attention head --------------
__global__ __launch_bounds__(256) void attn_kernel(
    const float* __restrict__ md, const float* __restrict__ bmm,
    const float* __restrict__ bs_dw, const float* __restrict__ bs_bn1,
    const float* __restrict__ bs_pw, const float* __restrict__ bs_bn2,
    const float* __restrict__ bl_dw, const float* __restrict__ bl_bn1,
    const float* __restrict__ bl_pw, const float* __restrict__ bl_bn2,
    const float* __restrict__ fuse_w, const float* __restrict__ fuse_b,
    float* __restrict__ attn)
{
    __shared__ float tile[20 * 20];
    __shared__ float mmred[2];
    int img = blockIdx.x >> 6;
    int t = blockIdx.x & 63;
    int y0 = (t >> 3) << 4, x0 = (t & 7) << 4;
    int tid = threadIdx.x;
    int ty = tid >> 4, tx = tid & 15;

    if (tid < 64) {
        float mn = bmm[(img * 64 + tid) * 2];
        float mx = bmm[(img * 64 + tid) * 2 + 1];
#pragma unroll
        for (int d = 32; d > 0; d >>= 1) {
            mn = fminf(mn, __shfl_xor(mn, d));
            mx = fmaxf(mx, __shfl_xor(mx, d));
        }
        if (tid == 0) { mmred[0] = mn; mmred[1] = mx; }
    }
    __syncthreads();

    float fdmin = mmred[0];
    float inv = 1.f / (mmred[1] - fdmin + 1e-6f);

    const float* mdi = md + img * HW;
    for (int l = tid; l < 400; l += 256) {
        int ly = l / 20, lx = l - ly * 20;
        int yy = y0 - 2 + ly, xx = x0 - 2 + lx;
        float v = 0.f;
        if (yy >= 0 && yy < H_IMG && xx >= 0 && xx < W_IMG)
            v = (mdi[yy * W_IMG + xx] - fdmin) * inv;
        tile[l] = v;
    }
    __syncthreads();

    float c3 = 0.f;
#pragma unroll
    for (int dy = 0; dy < 3; ++dy)
#pragma unroll
        for (int dx = 0; dx < 3; ++dx)
            c3 = fmaf(tile[(ty + 1 + dy) * 20 + tx + 1 + dx], bs_dw[dy * 3 + dx], c3);
    float c5 = 0.f;
#pragma unroll
    for (int dy = 0; dy < 5; ++dy)
#pragma unroll
        for (int dx = 0; dx < 5; ++dx)
            c5 = fmaf(tile[(ty + dy) * 20 + tx + dx], bl_dw[dy * 5 + dx], c5);

    float s1 = bs_bn1[0] * rsqrtf(bs_bn1[3] + BN_EPS);
    float t1 = silu_f(s1 * c3 + (bs_bn1[1] - bs_bn1[2] * s1));
    float s2 = bl_bn1[0] * rsqrtf(bl_bn1[3] + BN_EPS);
    float t2 = silu_f(s2 * c5 + (bl_bn1[1] - bl_bn1[2] * s2));

    float acc = fuse_b[0];
#pragma unroll
    for (int c = 0; c < 8; ++c) {
        float scs = bs_bn2[c] * rsqrtf(bs_bn2[24 + c] + BN_EPS);
        float u1 = silu_f(scs * (bs_pw[c] * t1) + (bs_bn2[8 + c] - bs_bn2[16 + c] * scs));
        acc = fmaf(fuse_w[c], u1, acc);
        float scl = bl_bn2[c] * rsqrtf(bl_bn2[24 + c] + BN_EPS);
        float u2 = silu_f(scl * (bl_pw[c] * t2) + (bl_bn2[8 + c] - bl_bn2[16 + c] * scl));
        acc = fmaf(fuse_w[8 + c], u2, acc);
    }
    attn[img * HW + (y0 + ty) * W_IMG + (x0 + tx)] = 1.f / (1.f + __expf(-acc));
}

// ---------------- D: out = x * (1 + gamma * attn), linear coalesced ----------
__global__ __launch_bounds__(256) void final_kernel(
    const float* __restrict__ x, const float* __restrict__ attn,
    const float* __restrict__ gamma, float* __restrict__ out)
{
    float g = gamma[0];
    size_t f4 = (size_t)blockIdx.x * 256 + threadIdx.x;
#pragma unroll
    for (int c = 0; c < 4; ++c) {
        size_t i = (f4 + (size_t)c * 1048576) * 4;   // float index
        int img_i = (int)(i >> 22);                  // / (256*16384)
        int hw    = (int)(i & (size_t)(HW - 1));
        float4 av = *(const float4*)(attn + ((size_t)img_i << 14) + hw);
        float4 xv = *(const float4*)(x + i);
        float4 o;
        o.x = xv.x * (1.f + g * av.x);
        o.y = xv.y * (1.f + g * av.y);
        o.z = xv.z * (1.f + g * av.z);
        o.w = xv.w * (1.f + g * av.w);
        *(float4*)(out + i) = o;
    }
}

extern "C" void kernel_launch(void* const* d_in, const int* in_sizes, int n_in,
                              void* d_out, int out_size, void* d_ws, size_t ws_size,
                              hipStream_t stream) {
    const float* x      = (const float*)d_in[0];
    const float* fp_w1  = (const float*)d_in[1];
    const float* fp_bn1 = (const float*)d_in[2];
    const float* fp_dw  = (const float*)d_in[3];
    const float* fp_bn2 = (const float*)d_in[4];
    const float* protos = (const float*)d_in[5];
    const float* bs_dw  = (const float*)d_in[6];
    const float* bs_bn1 = (const float*)d_in[7];
    const float* bs_pw  = (const float*)d_in[8];
    const float* bs_bn2 = (const float*)d_in[9];
    const float* bl_dw  = (const float*)d_in[10];
    const float* bl_bn1 = (const float*)d_in[11];
    const float* bl_pw  = (const float*)d_in[12];
    const float* bl_bn2 = (const float*)d_in[13];
    const float* fuse_w = (const float*)d_in[14];
    const float* fuse_b = (const float*)d_in[15];
    const float* gamma  = (const float*)d_in[16];
    float* ws  = (float*)d_ws;
    float* out = (float*)d_out;

    conv1x1_kernel<<<512, 512, 0, stream>>>(x, fp_w1, fp_bn1, (u16*)(ws + OFF_H));
    dwconv_dev_kernel<<<256, 1024, 0, stream>>>((const u16*)(ws + OFF_H), fp_dw, fp_bn2,
                                                protos, ws + OFF_MD, ws + OFF_BMM);
    attn_kernel<<<256, 256, 0, stream>>>(ws + OFF_MD, ws + OFF_BMM,
                                         bs_dw, bs_bn1, bs_pw, bs_bn2,
                                         bl_dw, bl_bn1, bl_pw, bl_bn2,
                                         fuse_w, fuse_b, ws + OFF_ATTN);
    final_kernel<<<4096, 256, 0, stream>>>(x, ws + OFF_ATTN, gamma, out);
}